// Round 4
// baseline (216.074 us; speedup 1.0000x reference)
//
#include <hip/hip_runtime.h>

#define B_  4
#define D_  512
#define H_  8
#define DV_ 64
#define S_  2048

typedef __bf16 bf16;
typedef bf16  bf16x8 __attribute__((ext_vector_type(8)));
typedef bf16  bf16x4 __attribute__((ext_vector_type(4)));
typedef float f32x4  __attribute__((ext_vector_type(4)));

#define MFMA(a, b, c) __builtin_amdgcn_mfma_f32_16x16x32_bf16((a), (b), (c), 0, 0, 0)

// async global->LDS, 16B per lane; LDS dest must be wave-uniform base + lane*16
#define GLOAD_LDS(g, l)                                                     \
    __builtin_amdgcn_global_load_lds(                                       \
        (const __attribute__((address_space(1))) void*)(g),                 \
        (__attribute__((address_space(3))) void*)(l), 16, 0, 0)

// ---------------------------------------------------------------------------
// Kernel 1: prep = transpose x (B,D,S fp32 -> B,S,D bf16)  +  pack weights
// (Wq|Wk|Wv|W0 fp32 -> Wb 2048x512 bf16, rows: [0,512)Q [512,1024)K
//  [1024,1536)V [1536,2048)W0)
// ---------------------------------------------------------------------------
__global__ __launch_bounds__(256) void prep(
    const float* __restrict__ x, const float* __restrict__ Wq,
    const float* __restrict__ Wk, const float* __restrict__ Wv,
    const float* __restrict__ W0, bf16* __restrict__ xb, bf16* __restrict__ Wb) {
    const int bid = blockIdx.x;
    if (bid < 4096) {                            // transpose part
        __shared__ float tile[32][33];
        const int sblk = bid % 64;               // S/32
        const int dblk = (bid / 64) % 16;        // D/32
        const int b    = bid / 1024;
        const int d0 = dblk * 32, s0 = sblk * 32;
        const int tx = threadIdx.x & 31;
        const int ty = threadIdx.x >> 5;         // 0..7
        const float* xp = x + (size_t)b * D_ * S_;
#pragma unroll
        for (int i = 0; i < 32; i += 8)
            tile[ty + i][tx] = xp[(size_t)(d0 + ty + i) * S_ + s0 + tx];
        __syncthreads();
        bf16* xbp = xb + ((size_t)b * S_ + s0) * D_ + d0;
#pragma unroll
        for (int i = 0; i < 32; i += 8)
            xbp[(size_t)(ty + i) * D_ + tx] = (bf16)tile[tx][ty + i];
    } else {                                     // weight-pack part: 256 blocks
        const int f0 = ((bid - 4096) * 256 + threadIdx.x) * 16;  // 0..1048560
        const int src = f0 >> 18;                // 262144 elems per matrix
        const int off = f0 & 262143;
        const float* W = (src == 0) ? Wq : (src == 1) ? Wk : (src == 2) ? Wv : W0;
        float4 v0 = *(const float4*)&W[off];
        float4 v1 = *(const float4*)&W[off + 4];
        float4 v2 = *(const float4*)&W[off + 8];
        float4 v3 = *(const float4*)&W[off + 12];
        bf16x8 h0 = {(bf16)v0.x, (bf16)v0.y, (bf16)v0.z, (bf16)v0.w,
                     (bf16)v1.x, (bf16)v1.y, (bf16)v1.z, (bf16)v1.w};
        bf16x8 h1 = {(bf16)v2.x, (bf16)v2.y, (bf16)v2.z, (bf16)v2.w,
                     (bf16)v3.x, (bf16)v3.y, (bf16)v3.z, (bf16)v3.w};
        *(bf16x8*)&Wb[f0]     = h0;
        *(bf16x8*)&Wb[f0 + 8] = h1;
    }
}

// ---------------------------------------------------------------------------
// Kernel 2: fused QKV GEMM, m97-style. A = xb (8192 x 512) bf16; B = Wb rows
// [0,1536). 128x128 tile, BK=64, global_load_lds(16B) into fragment-linear
// LDS (chunk c = mt*2+kk at (c*64+lane)*16B) -> conflict-free write AND read.
// ---------------------------------------------------------------------------
__global__ __launch_bounds__(256) void gemm_qkv(
    const bf16* __restrict__ A, const bf16* __restrict__ Wb,
    const float* __restrict__ bq, const float* __restrict__ bk,
    const float* __restrict__ bv,
    bf16* __restrict__ Q, bf16* __restrict__ K, bf16* __restrict__ Vt) {
    __shared__ bf16 Asl[8192];                   // 16 chunks * 64 lanes * 8
    __shared__ bf16 Bsl[8192];

    const int tid = threadIdx.x;
    const int w = tid >> 6, lane = tid & 63;
    const int m16 = lane & 15, quad = lane >> 4;
    const int wr = w & 1, wc = w >> 1;

    const int nblk = blockIdx.x % 12;            // N = 1536 / 128
    const int mblk = blockIdx.x / 12;            // M = 8192 / 128
    const int m0 = mblk * 128, n0 = nblk * 128;

    f32x4 acc[4][4];
#pragma unroll
    for (int i = 0; i < 4; ++i)
#pragma unroll
        for (int j = 0; j < 4; ++j) acc[i][j] = (f32x4){0.f, 0.f, 0.f, 0.f};

    for (int k0 = 0; k0 < D_; k0 += 64) {
        __syncthreads();
#pragma unroll
        for (int i = 0; i < 4; ++i) {            // wave w stages chunks w*4..w*4+3
            const int c  = w * 4 + i;
            const int mt = c >> 1, kk = c & 1;
            const int row = mt * 16 + m16;
            const int col = k0 + kk * 32 + quad * 8;
            GLOAD_LDS(&A[(size_t)(m0 + row) * D_ + col],  &Asl[(c * 64 + lane) * 8]);
            GLOAD_LDS(&Wb[(size_t)(n0 + row) * D_ + col], &Bsl[(c * 64 + lane) * 8]);
        }
        __syncthreads();
#pragma unroll
        for (int kk = 0; kk < 2; ++kk) {
            bf16x8 af[4], bfv[4];
#pragma unroll
            for (int t = 0; t < 4; ++t) {
                af[t]  = *(const bf16x8*)&Asl[(((wr * 4 + t) * 2 + kk) * 64 + lane) * 8];
                bfv[t] = *(const bf16x8*)&Bsl[(((wc * 4 + t) * 2 + kk) * 64 + lane) * 8];
            }
#pragma unroll
            for (int mt = 0; mt < 4; ++mt)
#pragma unroll
                for (int nt = 0; nt < 4; ++nt)
                    acc[mt][nt] = MFMA(af[mt], bfv[nt], acc[mt][nt]);
        }
    }

    const int proj = n0 >> 9;                    // 128-tiles never straddle
    const float* bias = (proj == 0) ? bq : (proj == 1) ? bk : bv;
#pragma unroll
    for (int mt = 0; mt < 4; ++mt)
#pragma unroll
        for (int nt = 0; nt < 4; ++nt) {
            const int nlin = n0 + wc * 64 + nt * 16 + m16;
            const int nr = nlin & 511;
            const int h = nr >> 6, e = nr & 63;
            const float bia = bias[nr];
            const int srow = m0 + wr * 64 + mt * 16 + quad * 4;
            const int b = srow >> 11, s = srow & 2047;
            if (proj == 2) {
                bf16x4 hv;
#pragma unroll
                for (int r = 0; r < 4; ++r) hv[r] = (bf16)(acc[mt][nt][r] + bia);
                *(bf16x4*)&Vt[(((size_t)b * H_ + h) * DV_ + e) * S_ + s] = hv;
            } else {
                bf16* dst = (proj == 0) ? Q : K;
#pragma unroll
                for (int r = 0; r < 4; ++r)
                    dst[(((size_t)b * H_ + h) * S_ + s + r) * DV_ + e] =
                        (bf16)(acc[mt][nt][r] + bia);
            }
        }
}

// ---------------------------------------------------------------------------
// Kernel 3: flash attention v4 — key-split waves + K/V register prefetch.
// ---------------------------------------------------------------------------
#define RS 36
__global__ __launch_bounds__(256, 2) void flash_attn(
    const bf16* __restrict__ Q, const bf16* __restrict__ K, const bf16* __restrict__ Vt,
    const float* __restrict__ mask, bf16* __restrict__ heads) {
    __shared__ union SMem {
        bf16 Ps[4][64][RS];                       // 18432 B, wave-local slices
        struct { float O[64][65]; float L[64]; } red;
    } sm;

    const int bidx = blockIdx.x;                 // B*H*(S/64) = 1024
    const int qblk = bidx & 31;
    const int h    = (bidx >> 5) & 7;
    const int b    = bidx >> 8;
    const int q0   = qblk * 64;

    const int tid = threadIdx.x;
    const int w = tid >> 6, lane = tid & 63;
    const int m16 = lane & 15, quad = lane >> 4;

    const bf16* Qp = Q  + ((size_t)b * H_ + h) * S_ * DV_;
    const bf16* Kp = K  + ((size_t)b * H_ + h) * S_ * DV_;
    const bf16* Vp = Vt + ((size_t)b * H_ + h) * DV_ * S_;
    const float* mp = mask + (size_t)b * S_;

    // Q A-frags for all 64 q-rows, pre-scaled by 1/sqrt(64) (exact in bf16)
    bf16x8 qf[4][2];
#pragma unroll
    for (int mt = 0; mt < 4; ++mt)
#pragma unroll
        for (int kk = 0; kk < 2; ++kk) {
            bf16x8 v = *(const bf16x8*)&Qp[(size_t)(q0 + mt * 16 + m16) * DV_ +
                                           kk * 32 + quad * 8];
#pragma unroll
            for (int i = 0; i < 8; ++i) v[i] = (bf16)((float)v[i] * 0.125f);
            qf[mt][kk] = v;
        }

    bf16x8 ones;
#pragma unroll
    for (int i = 0; i < 8; ++i) ones[i] = (bf16)1.0f;

    f32x4 o[4][4];                               // O^T[e=mt*16+quad*4+r][q=nt*16+m16]
    f32x4 lacc[4];
#pragma unroll
    for (int mt = 0; mt < 4; ++mt)
#pragma unroll
        for (int nt = 0; nt < 4; ++nt) o[mt][nt] = (f32x4){0.f, 0.f, 0.f, 0.f};
#pragma unroll
    for (int nt = 0; nt < 4; ++nt) lacc[nt] = (f32x4){0.f, 0.f, 0.f, 0.f};

    // prefetch pipeline: current K/V frags in registers
    bf16x8 kfc[2][2], vfc[4];
    {
        const int tw = w * 32;
#pragma unroll
        for (int nt = 0; nt < 2; ++nt)
#pragma unroll
            for (int kk = 0; kk < 2; ++kk)
                kfc[nt][kk] = *(const bf16x8*)&Kp[(size_t)(tw + nt * 16 + m16) * DV_ +
                                                  kk * 32 + quad * 8];
#pragma unroll
        for (int mt = 0; mt < 4; ++mt)
            vfc[mt] = *(const bf16x8*)&Vp[(size_t)(mt * 16 + m16) * S_ + tw + quad * 8];
    }

    for (int t0 = 0; t0 < S_; t0 += 128) {
        const int tw = t0 + w * 32;              // this wave's 32 keys
        const bool more = (t0 + 128) < S_;

        // issue next-iter K/V loads first (latency hidden under compute below)
        bf16x8 kfn[2][2], vfn[4];
        if (more) {
            const int twn = tw + 128;
#pragma unroll
            for (int nt = 0; nt < 2; ++nt)
#pragma unroll
                for (int kk = 0; kk < 2; ++kk)
                    kfn[nt][kk] = *(const bf16x8*)&Kp[(size_t)(twn + nt * 16 + m16) * DV_ +
                                                      kk * 32 + quad * 8];
#pragma unroll
            for (int mt = 0; mt < 4; ++mt)
                vfn[mt] = *(const bf16x8*)&Vp[(size_t)(mt * 16 + m16) * S_ + twn + quad * 8];
        }

        // scores S[64q][32t] for this wave's keys
        f32x4 sc[4][2];
#pragma unroll
        for (int mt = 0; mt < 4; ++mt)
#pragma unroll
            for (int nt = 0; nt < 2; ++nt) sc[mt][nt] = (f32x4){0.f, 0.f, 0.f, 0.f};
#pragma unroll
        for (int kk = 0; kk < 2; ++kk)
#pragma unroll
            for (int mt = 0; mt < 4; ++mt)
#pragma unroll
                for (int nt = 0; nt < 2; ++nt)
                    sc[mt][nt] = MFMA(qf[mt][kk], kfc[nt][kk], sc[mt][nt]);

        // key mask + exp, write P to wave-local LDS (conflict-free scatter)
        const float mk0 = mp[tw + m16],          mk1 = mp[tw + 16 + m16];
        const float ng0 = (1.0f - mk0) * -1e30f, ng1 = (1.0f - mk1) * -1e30f;
#pragma unroll
        for (int mt = 0; mt < 4; ++mt)
#pragma unroll
            for (int r = 0; r < 4; ++r) {
                const int row = mt * 16 + quad * 4 + r;
                sm.Ps[w][row][m16]      = (bf16)__expf(sc[mt][0][r] * mk0 + ng0);
                sm.Ps[w][row][16 + m16] = (bf16)__expf(sc[mt][1][r] * mk1 + ng1);
            }

        // P B-frags back from LDS (b128)
        bf16x8 pf[4];
#pragma unroll
        for (int nt = 0; nt < 4; ++nt)
            pf[nt] = *(const bf16x8*)&sm.Ps[w][nt * 16 + m16][quad * 8];
#pragma unroll
        for (int mt = 0; mt < 4; ++mt)
#pragma unroll
            for (int nt = 0; nt < 4; ++nt) o[mt][nt] = MFMA(vfc[mt], pf[nt], o[mt][nt]);
#pragma unroll
        for (int nt = 0; nt < 4; ++nt) lacc[nt] = MFMA(ones, pf[nt], lacc[nt]);

        if (more) {
#pragma unroll
            for (int nt = 0; nt < 2; ++nt)
#pragma unroll
                for (int kk = 0; kk < 2; ++kk) kfc[nt][kk] = kfn[nt][kk];
#pragma unroll
            for (int mt = 0; mt < 4; ++mt) vfc[mt] = vfn[mt];
        }
    }

    // ---- cross-wave reduction (turn-based accumulate into sm.red) ----
    __syncthreads();                             // all waves done with their Ps
#pragma unroll
    for (int ww = 0; ww < 4; ++ww) {
        if (w == ww) {
#pragma unroll
            for (int mt = 0; mt < 4; ++mt)
#pragma unroll
                for (int nt = 0; nt < 4; ++nt)
#pragma unroll
                    for (int r = 0; r < 4; ++r) {
                        float* slot = &sm.red.O[mt * 16 + quad * 4 + r][nt * 16 + m16];
                        *slot = (ww == 0) ? o[mt][nt][r] : (*slot + o[mt][nt][r]);
                    }
            if (quad == 0)
#pragma unroll
                for (int nt = 0; nt < 4; ++nt) {
                    float* ls = &sm.red.L[nt * 16 + m16];
                    *ls = (ww == 0) ? lacc[nt][0] : (*ls + lacc[nt][0]);
                }
        }
        __syncthreads();
    }

    // ---- final store: thread -> (q = tid>>2, 16-wide e-chunk = (tid&3)*16) ----
    const int ql = tid >> 2, ec = (tid & 3) * 16;
    const float l  = sm.red.L[ql];
    const float qm = mp[q0 + ql];
    const float inv = qm / l;
    bf16x8 hv[2];
#pragma unroll
    for (int c = 0; c < 2; ++c)
#pragma unroll
        for (int i = 0; i < 8; ++i)
            hv[c][i] = (bf16)(sm.red.O[ec + c * 8 + i][ql] * inv);
    bf16* dst = &heads[((size_t)b * S_ + q0 + ql) * D_ + h * DV_ + ec];
    *(bf16x8*)(dst)     = hv[0];
    *(bf16x8*)(dst + 8) = hv[1];
}

// ---------------------------------------------------------------------------
// Kernel 4: out projection, same m97-style core. B = Wb rows [1536,2048).
// out (B, D, S) fp32, float4 stores along s.
// ---------------------------------------------------------------------------
__global__ __launch_bounds__(256) void gemm_out(
    const bf16* __restrict__ A, const bf16* __restrict__ Wb,
    const float* __restrict__ b0, float* __restrict__ outp) {
    __shared__ bf16 Asl[8192];
    __shared__ bf16 Bsl[8192];

    const int tid = threadIdx.x;
    const int w = tid >> 6, lane = tid & 63;
    const int m16 = lane & 15, quad = lane >> 4;
    const int wr = w & 1, wc = w >> 1;

    const int nblk = blockIdx.x & 3;             // N = 512 / 128
    const int mblk = blockIdx.x >> 2;            // M = 8192 / 128
    const int m0 = mblk * 128, n0 = nblk * 128;

    f32x4 acc[4][4];
#pragma unroll
    for (int i = 0; i < 4; ++i)
#pragma unroll
        for (int j = 0; j < 4; ++j) acc[i][j] = (f32x4){0.f, 0.f, 0.f, 0.f};

    for (int k0 = 0; k0 < D_; k0 += 64) {
        __syncthreads();
#pragma unroll
        for (int i = 0; i < 4; ++i) {
            const int c  = w * 4 + i;
            const int mt = c >> 1, kk = c & 1;
            const int row = mt * 16 + m16;
            const int col = k0 + kk * 32 + quad * 8;
            GLOAD_LDS(&A[(size_t)(m0 + row) * D_ + col], &Asl[(c * 64 + lane) * 8]);
            GLOAD_LDS(&Wb[(size_t)(1536 + n0 + row) * D_ + col], &Bsl[(c * 64 + lane) * 8]);
        }
        __syncthreads();
#pragma unroll
        for (int kk = 0; kk < 2; ++kk) {
            bf16x8 af[4], bfv[4];
#pragma unroll
            for (int t = 0; t < 4; ++t) {
                af[t]  = *(const bf16x8*)&Asl[(((wr * 4 + t) * 2 + kk) * 64 + lane) * 8];
                bfv[t] = *(const bf16x8*)&Bsl[(((wc * 4 + t) * 2 + kk) * 64 + lane) * 8];
            }
#pragma unroll
            for (int mt = 0; mt < 4; ++mt)
#pragma unroll
                for (int nt = 0; nt < 4; ++nt)
                    acc[mt][nt] = MFMA(af[mt], bfv[nt], acc[mt][nt]);
        }
    }

#pragma unroll
    for (int mt = 0; mt < 4; ++mt)
#pragma unroll
        for (int nt = 0; nt < 4; ++nt) {
            const int n = n0 + wc * 64 + nt * 16 + m16;
            const float bia = b0[n];
            const int srow = m0 + wr * 64 + mt * 16 + quad * 4;
            const int b = srow >> 11, s = srow & 2047;
            float4 vv;
            vv.x = acc[mt][nt][0] + bia;
            vv.y = acc[mt][nt][1] + bia;
            vv.z = acc[mt][nt][2] + bia;
            vv.w = acc[mt][nt][3] + bia;
            *(float4*)&outp[((size_t)b * D_ + n) * S_ + s] = vv;
        }
}

// ---------------------------------------------------------------------------
extern "C" void kernel_launch(void* const* d_in, const int* in_sizes, int n_in,
                              void* d_out, int out_size, void* d_ws, size_t ws_size,
                              hipStream_t stream) {
    const float* x    = (const float*)d_in[0];
    const float* mask = (const float*)d_in[1];
    const float* Wq   = (const float*)d_in[2];
    const float* bq   = (const float*)d_in[3];
    const float* Wk   = (const float*)d_in[4];
    const float* bk   = (const float*)d_in[5];
    const float* Wv   = (const float*)d_in[6];
    const float* bv   = (const float*)d_in[7];
    const float* W0   = (const float*)d_in[8];
    const float* b0   = (const float*)d_in[9];
    float* out = (float*)d_out;

    char* ws = (char*)d_ws;
    const size_t SEG = (size_t)B_ * S_ * D_ * sizeof(bf16);   // 8 MiB
    bf16* xb    = (bf16*)(ws);            // reused as `heads` after gemm_qkv
    bf16* Qb    = (bf16*)(ws + SEG);
    bf16* Kb    = (bf16*)(ws + 2 * SEG);
    bf16* Vt    = (bf16*)(ws + 3 * SEG);
    bf16* Wb    = (bf16*)(ws + 4 * SEG);  // 2048x512 bf16 = 2 MiB
    bf16* heads = xb;

    prep<<<dim3(4096 + 256), dim3(256), 0, stream>>>(x, Wq, Wk, Wv, W0, xb, Wb);
    gemm_qkv<<<dim3(64 * 12), dim3(256), 0, stream>>>(xb, Wb, bq, bk, bv, Qb, Kb, Vt);
    flash_attn<<<dim3(B_ * H_ * (S_ / 64)), dim3(256), 0, stream>>>(Qb, Kb, Vt, mask, heads);
    gemm_out<<<dim3(64 * 4), dim3(256), 0, stream>>>(heads, Wb, b0, out);
}